// Round 8
// baseline (21.451 us; speedup 1.0000x reference)
//
#include <hip/hip_runtime.h>

#define IMG_W 256
#define IMG_H 256
#define NG 512
#define NSEG 16
#define SEGLEN (NG / NSEG)   // 32
#define PXT 64               // u-threads per block
#define PPT 4                // pixels per thread: u, u+64, u+128, u+192
#define FOCAL 50.0f

// One block per image row, 1024 threads = 64 u-threads x 16 depth-segments,
// 4 pixels per thread. Phase 1: block-local stable depth sort (u64 keys,
// split rank count) + per-row folding c = b*dv^2 + log2(opac) + per-row
// cull interval [lo,hi] (u-range where e >= -25; empty if row missed).
// Phase 2: composite with wave-uniform skip at row AND 64-px-window grain.
__global__ __launch_bounds__(1024, 1) void fused_kernel(
    const float* __restrict__ means3d, const float* __restrict__ scales,
    const float* __restrict__ opac, const float* __restrict__ colors,
    float* __restrict__ out)
{
    __shared__ __align__(16) unsigned long long zkey[NG];  // 4 KB
    __shared__ int rpart[NG];                    // 2 KB upper-half partial ranks
    __shared__ float4 g0[NG];                    // lo, hi, pu, a      (8 KB)
    __shared__ float4 g1[NG];                    // c, cr, cg, cb      (8 KB)
    __shared__ float4 part[NSEG][PPT][PXT];      // 64 KB segment partials

    const int tid = threadIdx.x;
    const int i = tid & (NG - 1);                // gaussian id for prep (both halves)

    // ---- phase 1: keys ----
    float z = 0.0f, mx = 0.0f, my = 0.0f;
    if (tid < NG) {
        mx = means3d[3 * i];
        my = means3d[3 * i + 1];
        z  = fmaxf(means3d[3 * i + 2], 0.1f);
        zkey[i] = ((unsigned long long)__float_as_uint(z) << 32) | (unsigned)i;
    }
    __syncthreads();

    // ---- phase 1: split rank count (thread i counts keys [0,256), i+512 counts [256,512)) ----
    const unsigned long long mykey = zkey[i];    // from LDS: valid for both halves
    int cnt = 0;
    {
        const ulonglong2* kp = (const ulonglong2*)zkey + ((tid >> 9) * (NG / 4));
        #pragma unroll 8
        for (int jj = 0; jj < NG / 4; ++jj) {    // 128 iters, 2 keys per b128 broadcast read
            const ulonglong2 kk = kp[jj];
            cnt += (kk.x < mykey);
            cnt += (kk.y < mykey);
        }
    }
    if (tid >= NG) rpart[i] = cnt;               // upper half publishes its partial
    __syncthreads();

    if (tid < NG) {
        const float inv_z = 1.0f / z;
        const float pu = FOCAL * mx * inv_z;
        const float pv = FOCAL * my * inv_z;
        const float su = fmaxf(FOCAL * scales[3 * i] * inv_z, 0.5f);
        const float sv = fmaxf(FOCAL * scales[3 * i + 1] * inv_z, 0.5f);
        const float k = -0.5f * 1.44269504088896340736f;  // -log2(e)/2
        const float a = k / (su * su);
        const float b = k / (sv * sv);
        const float lop = __log2f(opac[i]);
        // per-row fold: dv constant for this block's row
        const float dv = (float)blockIdx.x - (float)(IMG_H / 2) - pv;
        const float c = fmaf(dv * dv, b, lop);
        // cull interval: e = a*du^2 + c >= -25  =>  |du| <= sqrt((c+25)/(-a))
        // (alpha < 2^-25 cannot perturb f32 T or accumulators)
        float lo = 1e9f, hi = 1e9f;              // empty (row missed) by default
        const float r2 = (c + 25.0f) / (-a);     // a < 0 always
        if (r2 > 0.0f) {
            const float R = sqrtf(r2);
            lo = pu - R;
            hi = pu + R;
        }
        const int rank = cnt + rpart[i];         // unique: keys are distinct
        g0[rank] = make_float4(lo, hi, pu, a);
        g1[rank] = make_float4(c, colors[3 * i], colors[3 * i + 1], colors[3 * i + 2]);
    }
    __syncthreads();

    // ---- phase 2: raster, 4 px/thread, wave-uniform cull (row + 64-px window) ----
    const int p   = tid & (PXT - 1);
    const int seg = tid >> 6;                    // 0..15; one wave = one seg

    float u[PPT];
    #pragma unroll
    for (int j = 0; j < PPT; ++j) u[j] = (float)(p + PXT * j) - (float)(IMG_W / 2);

    float T[PPT], ar[PPT], ag[PPT], ab[PPT];
    #pragma unroll
    for (int j = 0; j < PPT; ++j) { T[j] = 1.0f; ar[j] = 0.0f; ag[j] = 0.0f; ab[j] = 0.0f; }

    const int base = seg * SEGLEN;
    #pragma unroll 4
    for (int n = 0; n < SEGLEN; ++n) {
        const float4 q0 = g0[base + n];          // lo, hi, pu, a (uniform broadcast)
        if (q0.y < -128.0f || q0.x > 127.0f) continue;   // dead for the whole row
        const float4 q1 = g1[base + n];          // c, cr, cg, cb
        #pragma unroll
        for (int j = 0; j < PPT; ++j) {
            // wave-uniform 64-px window for this j: u in [64j-128, 64j-65]
            const float slo = (float)(PXT * j - IMG_W / 2);
            const float shi = (float)(PXT * j - IMG_W / 2 + PXT - 1);
            if (q0.y < slo || q0.x > shi) continue;      // window dead (execz skip)
            const float du = u[j] - q0.z;
            const float e = fmaf(du * du, q0.w, q1.x);       // a*du^2 + c
            const float al = __builtin_amdgcn_exp2f(e);      // v_exp_f32
            const float w = al * T[j];
            ar[j] = fmaf(w, q1.y, ar[j]);
            ag[j] = fmaf(w, q1.z, ag[j]);
            ab[j] = fmaf(w, q1.w, ab[j]);
            T[j] -= w;                           // T *= (1 - alpha)
        }
    }

    // ---- combine: all segs publish, 4 waves (j-slices) reduce in parallel ----
    #pragma unroll
    for (int j = 0; j < PPT; ++j)
        part[seg][j][p] = make_float4(ar[j], ag[j], ab[j], T[j]);
    __syncthreads();

    if (tid < PPT * PXT) {                       // waves 0..3
        const int w  = tid >> 6;                 // j-slice
        const int pp = tid & (PXT - 1);
        float4 acc = part[0][w][pp];             // front segment
        #pragma unroll
        for (int s = 1; s < NSEG; ++s) {
            const float4 q = part[s][w][pp];     // conflict-free: lane-contiguous 16B
            acc.x = fmaf(acc.w, q.x, acc.x);
            acc.y = fmaf(acc.w, q.y, acc.y);
            acc.z = fmaf(acc.w, q.z, acc.z);
            acc.w *= q.w;
        }
        const int pid = blockIdx.x * IMG_W + (w * PXT + pp);
        out[3 * pid]     = acc.x;
        out[3 * pid + 1] = acc.y;
        out[3 * pid + 2] = acc.z;
    }
}

extern "C" void kernel_launch(void* const* d_in, const int* in_sizes, int n_in,
                              void* d_out, int out_size, void* d_ws, size_t ws_size,
                              hipStream_t stream) {
    const float* means3d = (const float*)d_in[0];
    const float* scales  = (const float*)d_in[1];
    const float* opac    = (const float*)d_in[2];
    const float* colors  = (const float*)d_in[3];
    float* out = (float*)d_out;

    fused_kernel<<<IMG_H, 1024, 0, stream>>>(means3d, scales, opac, colors, out);
}

// Round 9
// 20.553 us; speedup vs baseline: 1.0437x; 1.0437x over previous
//
#include <hip/hip_runtime.h>

#define IMG_W 256
#define IMG_H 256
#define NG 512
#define NSEG 16
#define SEGLEN (NG / NSEG)   // 32
#define PXT 64               // u-threads per block
#define PPT 4                // pixels per thread: u, u+64, u+128, u+192
#define FOCAL 50.0f

// One block per image row, 1024 threads = 64 u-threads x 16 depth-segments,
// 4 pixels per thread. Phase 1: block-local stable depth sort (u64 keys,
// split rank count) + per-row folding c = b*dv^2 + log2(opac) + per-row
// cull interval [lo,hi] (u-range where e >= -25; empty if row missed).
// Phase 2: composite with wave-uniform row-grain skip of dead gaussians.
// (R8 lesson: finer 64-px-window culling regresses — wide z-clipped
// gaussians span all windows; extra per-iter branches cost more than skips.)
__global__ __launch_bounds__(1024, 1) void fused_kernel(
    const float* __restrict__ means3d, const float* __restrict__ scales,
    const float* __restrict__ opac, const float* __restrict__ colors,
    float* __restrict__ out)
{
    __shared__ __align__(16) unsigned long long zkey[NG];  // 4 KB
    __shared__ int rpart[NG];                    // 2 KB upper-half partial ranks
    __shared__ float4 g0[NG];                    // lo, hi, pu, a      (8 KB)
    __shared__ float4 g1[NG];                    // c, cr, cg, cb      (8 KB)
    __shared__ float4 part[NSEG][PPT][PXT];      // 64 KB segment partials

    const int tid = threadIdx.x;
    const int i = tid & (NG - 1);                // gaussian id for prep (both halves)

    // ---- phase 1: keys ----
    float z = 0.0f, mx = 0.0f, my = 0.0f;
    if (tid < NG) {
        mx = means3d[3 * i];
        my = means3d[3 * i + 1];
        z  = fmaxf(means3d[3 * i + 2], 0.1f);
        zkey[i] = ((unsigned long long)__float_as_uint(z) << 32) | (unsigned)i;
    }
    __syncthreads();

    // ---- phase 1: split rank count (thread i counts keys [0,256), i+512 counts [256,512)) ----
    const unsigned long long mykey = zkey[i];    // from LDS: valid for both halves
    int cnt = 0;
    {
        const ulonglong2* kp = (const ulonglong2*)zkey + ((tid >> 9) * (NG / 4));
        #pragma unroll 8
        for (int jj = 0; jj < NG / 4; ++jj) {    // 128 iters, 2 keys per b128 broadcast read
            const ulonglong2 kk = kp[jj];
            cnt += (kk.x < mykey);
            cnt += (kk.y < mykey);
        }
    }
    if (tid >= NG) rpart[i] = cnt;               // upper half publishes its partial
    __syncthreads();

    if (tid < NG) {
        const float inv_z = 1.0f / z;
        const float pu = FOCAL * mx * inv_z;
        const float pv = FOCAL * my * inv_z;
        const float su = fmaxf(FOCAL * scales[3 * i] * inv_z, 0.5f);
        const float sv = fmaxf(FOCAL * scales[3 * i + 1] * inv_z, 0.5f);
        const float k = -0.5f * 1.44269504088896340736f;  // -log2(e)/2
        const float a = k / (su * su);
        const float b = k / (sv * sv);
        const float lop = __log2f(opac[i]);
        // per-row fold: dv constant for this block's row
        const float dv = (float)blockIdx.x - (float)(IMG_H / 2) - pv;
        const float c = fmaf(dv * dv, b, lop);
        // cull interval: e = a*du^2 + c >= -25  =>  |du| <= sqrt((c+25)/(-a))
        // (alpha < 2^-25 cannot perturb f32 T or accumulators)
        float lo = 1e9f, hi = 1e9f;              // empty (row missed) by default
        const float r2 = (c + 25.0f) / (-a);     // a < 0 always
        if (r2 > 0.0f) {
            const float R = sqrtf(r2);
            lo = pu - R;
            hi = pu + R;
        }
        const int rank = cnt + rpart[i];         // unique: keys are distinct
        g0[rank] = make_float4(lo, hi, pu, a);
        g1[rank] = make_float4(c, colors[3 * i], colors[3 * i + 1], colors[3 * i + 2]);
    }
    __syncthreads();

    // ---- phase 2: raster, 4 px/thread, wave-uniform row-grain cull ----
    const int p   = tid & (PXT - 1);
    const int seg = tid >> 6;                    // 0..15; one wave = one seg

    float u[PPT];
    #pragma unroll
    for (int j = 0; j < PPT; ++j) u[j] = (float)(p + PXT * j) - (float)(IMG_W / 2);

    float T[PPT], ar[PPT], ag[PPT], ab[PPT];
    #pragma unroll
    for (int j = 0; j < PPT; ++j) { T[j] = 1.0f; ar[j] = 0.0f; ag[j] = 0.0f; ab[j] = 0.0f; }

    const int base = seg * SEGLEN;
    #pragma unroll 4
    for (int n = 0; n < SEGLEN; ++n) {
        const float4 q0 = g0[base + n];          // lo, hi, pu, a (uniform broadcast)
        if (q0.y < -128.0f || q0.x > 127.0f) continue;   // dead for the whole row
        const float4 q1 = g1[base + n];          // c, cr, cg, cb
        #pragma unroll
        for (int j = 0; j < PPT; ++j) {
            const float du = u[j] - q0.z;
            const float e = fmaf(du * du, q0.w, q1.x);       // a*du^2 + c
            const float al = __builtin_amdgcn_exp2f(e);      // v_exp_f32
            const float w = al * T[j];
            ar[j] = fmaf(w, q1.y, ar[j]);
            ag[j] = fmaf(w, q1.z, ag[j]);
            ab[j] = fmaf(w, q1.w, ab[j]);
            T[j] -= w;                           // T *= (1 - alpha)
        }
    }

    // ---- combine: all segs publish, 4 waves (j-slices) reduce in parallel ----
    #pragma unroll
    for (int j = 0; j < PPT; ++j)
        part[seg][j][p] = make_float4(ar[j], ag[j], ab[j], T[j]);
    __syncthreads();

    if (tid < PPT * PXT) {                       // waves 0..3
        const int w  = tid >> 6;                 // j-slice
        const int pp = tid & (PXT - 1);
        float4 acc = part[0][w][pp];             // front segment
        #pragma unroll
        for (int s = 1; s < NSEG; ++s) {
            const float4 q = part[s][w][pp];     // conflict-free: lane-contiguous 16B
            acc.x = fmaf(acc.w, q.x, acc.x);
            acc.y = fmaf(acc.w, q.y, acc.y);
            acc.z = fmaf(acc.w, q.z, acc.z);
            acc.w *= q.w;
        }
        const int pid = blockIdx.x * IMG_W + (w * PXT + pp);
        out[3 * pid]     = acc.x;
        out[3 * pid + 1] = acc.y;
        out[3 * pid + 2] = acc.z;
    }
}

extern "C" void kernel_launch(void* const* d_in, const int* in_sizes, int n_in,
                              void* d_out, int out_size, void* d_ws, size_t ws_size,
                              hipStream_t stream) {
    const float* means3d = (const float*)d_in[0];
    const float* scales  = (const float*)d_in[1];
    const float* opac    = (const float*)d_in[2];
    const float* colors  = (const float*)d_in[3];
    float* out = (float*)d_out;

    fused_kernel<<<IMG_H, 1024, 0, stream>>>(means3d, scales, opac, colors, out);
}